// Round 2
// baseline (323.415 us; speedup 1.0000x reference)
//
#include <hip/hip_runtime.h>
#include <hip/hip_bf16.h>
#include <math.h>

#define MDIM 24
#define ZDIM 1024
#define NEG_INF_F -1e30f
#define EPS_F 1e-12f
#define NCH 32   // i-chunks per sector in k3

// ws layout (float offsets)
enum {
  OFF_U    = 0,            // U_ni            [24][1024]
  OFF_RMAX = 24576,        // loc-logit max   [24][1024]
  OFF_SEXP = 49152,        // loc sumexp      [24][1024]
  OFF_D    = 73728,        // D_ni            [24][1024]
  OFF_XP   = 98304         // X_pred          [24][1024]
};

// ---- mask handling: bool masks may arrive as packed bytes or 32-bit words.
// 32-bit words are 0 / 1 (int) or 0 / 0x3F800000 (float) -> word!=0 works for
// both. Packed bytes produce words like 0x01010100 -> detect and read bytes.
__device__ __forceinline__ bool masks_are_bytes(const void* hm, const void* gm) {
  const unsigned int* hw = (const unsigned int*)hm;
  const unsigned int* gw = (const unsigned int*)gm;
  bool b = false;
  #pragma unroll
  for (int k = 0; k < 6; k++) {   // first 24 bytes of each — safe in all layouts
    unsigned int a = hw[k], c = gw[k];
    if (a != 0u && a != 1u && a != 0x3F800000u) b = true;
    if (c != 0u && c != 1u && c != 0x3F800000u) b = true;
  }
  return b;
}
__device__ __forceinline__ bool loc_flag(const void* hm, const void* gm, int n) {
  bool bytes = masks_are_bytes(hm, gm);
  bool hv = bytes ? (((const unsigned char*)hm)[n] != 0)
                  : (((const unsigned int*)hm)[n] != 0u);
  bool gv = bytes ? (((const unsigned char*)gm)[n] != 0)
                  : (((const unsigned int*)gm)[n] != 0u);
  return gv && !hv;
}

// K1: per-(n,i) row — location-softmax stats + composite disutility U_ni.
// 256 threads = 4 waves = 4 rows, all same sector n; per-n rows staged in LDS.
__global__ __launch_bounds__(256) void k1_rows(
    const float* __restrict__ t, const float* __restrict__ price,
    const float* __restrict__ h, const float* __restrict__ A_ni,
    const float* __restrict__ beta, const float* __restrict__ lamda,
    const void* __restrict__ housing, const void* __restrict__ genflux,
    float* __restrict__ ws) {
  const int n  = blockIdx.x >> 8;            // 256 blocks per sector
  const int i0 = (blockIdx.x & 255) * 4;
  __shared__ float pc_s[ZDIM];               // lamda*(price+h)
  __shared__ float cc_s[ZDIM];               // slog(A) - beta*pc
  const float bn = beta[n], ln = lamda[n];
  for (int j = threadIdx.x; j < ZDIM; j += 256) {
    float pc = ln * (price[n * ZDIM + j] + h[n * ZDIM + j]);
    float sa = logf(fmaxf(A_ni[n * ZDIM + j], EPS_F));
    pc_s[j] = pc;
    cc_s[j] = sa - bn * pc;
  }
  __syncthreads();
  const int wave = threadIdx.x >> 6, lane = threadIdx.x & 63;
  const int i = i0 + wave;
  const int row = n * ZDIM + i;
  if (!loc_flag(housing, genflux, n)) {
    // Pr = eye  =>  U_ni = U_nij[i,i]
    if (lane == 0)
      ws[OFF_U + row] = pc_s[i] + t[(size_t)row * ZDIM + i];
    return;
  }
  const float4* t4  = (const float4*)(t + (size_t)row * ZDIM);
  const float4* pc4 = (const float4*)pc_s;
  const float4* cc4 = (const float4*)cc_s;
  float lg[16], uv[16];
  float mx = -INFINITY;
  #pragma unroll
  for (int k = 0; k < 4; k++) {
    const int f = lane + 64 * k;
    float4 tv = t4[f];
    float4 pv = pc4[f];
    float4 cv = cc4[f];
    uv[4*k+0] = pv.x + tv.x;  lg[4*k+0] = cv.x - bn * tv.x;
    uv[4*k+1] = pv.y + tv.y;  lg[4*k+1] = cv.y - bn * tv.y;
    uv[4*k+2] = pv.z + tv.z;  lg[4*k+2] = cv.z - bn * tv.z;
    uv[4*k+3] = pv.w + tv.w;  lg[4*k+3] = cv.w - bn * tv.w;
    mx = fmaxf(mx, fmaxf(fmaxf(lg[4*k], lg[4*k+1]), fmaxf(lg[4*k+2], lg[4*k+3])));
  }
  #pragma unroll
  for (int off = 32; off >= 1; off >>= 1)
    mx = fmaxf(mx, __shfl_xor(mx, off));
  float se = 0.f, su = 0.f;
  #pragma unroll
  for (int k = 0; k < 16; k++) {
    float e = __expf(lg[k] - mx);
    se += e;
    su = fmaf(e, uv[k], su);
  }
  #pragma unroll
  for (int off = 32; off >= 1; off >>= 1) {
    se += __shfl_xor(se, off);
    su += __shfl_xor(su, off);
  }
  if (lane == 0) {
    ws[OFF_U + row]    = su / se;
    ws[OFF_RMAX + row] = mx;
    ws[OFF_SEXP + row] = se;
  }
}

// K2: substitution softmax over n + total demand D_ni. One thread per zone i.
__global__ __launch_bounds__(64) void k2_demand(
    const float* __restrict__ demin, const float* __restrict__ demax,
    const float* __restrict__ delta, const float* __restrict__ omega,
    const float* __restrict__ sigma, const float* __restrict__ Kn,
    const float* __restrict__ attractor, const float* __restrict__ exogd,
    const float* __restrict__ X0, const float* __restrict__ exogp,
    const void* __restrict__ housing, const void* __restrict__ genflux,
    float* __restrict__ ws) {
  const int i = blockIdx.x * 64 + threadIdx.x;   // 0..1023
  float Uv[MDIM], asl[MDIM], acc[MDIM];
  #pragma unroll
  for (int n = 0; n < MDIM; n++) {
    Uv[n]  = ws[OFF_U + n * ZDIM + i];
    asl[n] = logf(fmaxf(attractor[n * ZDIM + i], EPS_F));
    acc[n] = 0.f;
  }
  for (int m = 0; m < MDIM; m++) {
    float sig = sigma[m];
    float Xt  = X0[m * ZDIM + i] + exogp[m * ZDIM + i];
    float a[MDIM], lg[MDIM];
    float mx = -INFINITY;
    int any = 0;
    #pragma unroll
    for (int n = 0; n < MDIM; n++) {
      float dm = demin[m * MDIM + n];
      float dd = demax[m * MDIM + n] - dm;
      float av = dm + dd * __expf(-delta[m * MDIM + n] * Uv[n]);
      a[n] = av;
      if (Kn[m * MDIM + n] > 0.f) {
        float l = asl[n] - sig * omega[m * MDIM + n] * av * Uv[n];
        lg[n] = l; any = 1;
        mx = fmaxf(mx, l);
      } else {
        lg[n] = NEG_INF_F;
      }
    }
    if (any) {
      float se = 0.f;
      #pragma unroll
      for (int n = 0; n < MDIM; n++)
        if (Kn[m * MDIM + n] > 0.f) se += __expf(lg[n] - mx);
      float inv = 1.f / se;
      #pragma unroll
      for (int n = 0; n < MDIM; n++) {
        float S = (Kn[m * MDIM + n] > 0.f) ? __expf(lg[n] - mx) * inv : 1.f;
        acc[n] = fmaf(a[n] * S, Xt, acc[n]);
      }
    } else {
      #pragma unroll
      for (int n = 0; n < MDIM; n++) acc[n] = fmaf(a[n], Xt, acc[n]);  // S == 1
    }
  }
  #pragma unroll
  for (int n = 0; n < MDIM; n++) {
    float Dv = exogd[n * ZDIM + i] + acc[n];
    ws[OFF_D + n * ZDIM + i]  = Dv;
    // eye-sector X_pred = D; loc sectors accumulated by k3 from 0
    ws[OFF_XP + n * ZDIM + i] = loc_flag(housing, genflux, n) ? 0.f : Dv;
  }
}

// K3: X_pred[n,j] += sum_i (D_i/sumexp_i) * exp(c_j - max_i - beta*t[n,i,j])
// grid = (n, i-chunk); loc sectors only; second (L3-warm) pass over t.
__global__ __launch_bounds__(256) void k3_xpred(
    const float* __restrict__ t, const float* __restrict__ price,
    const float* __restrict__ h, const float* __restrict__ A_ni,
    const float* __restrict__ beta, const float* __restrict__ lamda,
    const void* __restrict__ housing, const void* __restrict__ genflux,
    float* __restrict__ ws) {
  const int n = blockIdx.x / NCH, ic = blockIdx.x % NCH;
  if (!loc_flag(housing, genflux, n)) return;
  const int tj = threadIdx.x;                       // float4 index over j
  const float bn = beta[n], ln = lamda[n];
  const float4 pr = ((const float4*)(price + n * ZDIM))[tj];
  const float4 hh = ((const float4*)(h     + n * ZDIM))[tj];
  const float4 aa = ((const float4*)(A_ni  + n * ZDIM))[tj];
  const float c0 = logf(fmaxf(aa.x, EPS_F)) - bn * (ln * (pr.x + hh.x));
  const float c1 = logf(fmaxf(aa.y, EPS_F)) - bn * (ln * (pr.y + hh.y));
  const float c2 = logf(fmaxf(aa.z, EPS_F)) - bn * (ln * (pr.z + hh.z));
  const float c3 = logf(fmaxf(aa.w, EPS_F)) - bn * (ln * (pr.w + hh.w));
  const float4* t4 = (const float4*)t;
  float x0 = 0.f, x1 = 0.f, x2 = 0.f, x3 = 0.f;
  for (int ii = 0; ii < ZDIM / NCH; ii++) {
    const int i = ic * (ZDIM / NCH) + ii;
    const int row = n * ZDIM + i;
    const float mx = ws[OFF_RMAX + row];
    const float w  = ws[OFF_D + row] / ws[OFF_SEXP + row];
    float4 tv = t4[(size_t)row * (ZDIM / 4) + tj];
    x0 = fmaf(w, __expf(c0 - mx - bn * tv.x), x0);
    x1 = fmaf(w, __expf(c1 - mx - bn * tv.y), x1);
    x2 = fmaf(w, __expf(c2 - mx - bn * tv.z), x2);
    x3 = fmaf(w, __expf(c3 - mx - bn * tv.w), x3);
  }
  float* xp = ws + OFF_XP + n * ZDIM + tj * 4;
  atomicAdd(xp + 0, x0);
  atomicAdd(xp + 1, x1);
  atomicAdd(xp + 2, x2);
  atomicAdd(xp + 3, x3);
}

// K4: loss = mean((X_pred - X_target)^2). Single block -> direct write, no memset.
__global__ __launch_bounds__(1024) void k4_loss(
    const float* __restrict__ Xtg, const float* __restrict__ ws,
    float* __restrict__ out) {
  float s = 0.f;
  for (int e = threadIdx.x; e < MDIM * ZDIM; e += 1024) {
    float d = ws[OFF_XP + e] - Xtg[e];
    s = fmaf(d, d, s);
  }
  #pragma unroll
  for (int off = 32; off >= 1; off >>= 1) s += __shfl_xor(s, off);
  __shared__ float red[16];
  const int w = threadIdx.x >> 6, lane = threadIdx.x & 63;
  if (lane == 0) red[w] = s;
  __syncthreads();
  if (threadIdx.x == 0) {
    float tot = 0.f;
    #pragma unroll
    for (int k = 0; k < 16; k++) tot += red[k];
    *out = tot * (1.0f / (MDIM * ZDIM));
  }
}

extern "C" void kernel_launch(void* const* d_in, const int* in_sizes, int n_in,
                              void* d_out, int out_size, void* d_ws, size_t ws_size,
                              hipStream_t stream) {
  (void)in_sizes; (void)n_in; (void)out_size; (void)ws_size;
  const float* h       = (const float*)d_in[0];
  const float* price   = (const float*)d_in[1];
  const float* t       = (const float*)d_in[2];
  const float* demin   = (const float*)d_in[3];
  const float* demax   = (const float*)d_in[4];
  const float* delta   = (const float*)d_in[5];
  const float* omega   = (const float*)d_in[6];
  const float* sigma   = (const float*)d_in[7];
  const float* Kn      = (const float*)d_in[8];
  const float* attract = (const float*)d_in[9];
  const float* beta    = (const float*)d_in[10];
  const float* lamda   = (const float*)d_in[11];
  const float* A_ni    = (const float*)d_in[12];
  const float* exogd   = (const float*)d_in[13];
  const float* exogp   = (const float*)d_in[14];
  const float* X0      = (const float*)d_in[15];
  const float* Xtg     = (const float*)d_in[16];
  const void*  housing = d_in[17];
  const void*  genflux = d_in[18];
  float* ws  = (float*)d_ws;
  float* out = (float*)d_out;

  k1_rows<<<MDIM * 256, 256, 0, stream>>>(t, price, h, A_ni, beta, lamda,
                                          housing, genflux, ws);
  k2_demand<<<16, 64, 0, stream>>>(demin, demax, delta, omega, sigma, Kn,
                                   attract, exogd, X0, exogp, housing, genflux, ws);
  k3_xpred<<<MDIM * NCH, 256, 0, stream>>>(t, price, h, A_ni, beta, lamda,
                                           housing, genflux, ws);
  k4_loss<<<1, 1024, 0, stream>>>(Xtg, ws, out);
}

// Round 3
// 237.031 us; speedup vs baseline: 1.3644x; 1.3644x over previous
//
#include <hip/hip_runtime.h>
#include <hip/hip_bf16.h>
#include <math.h>

#define MDIM 24
#define ZDIM 1024
#define NEG_INF_F -1e30f
#define EPS_F 1e-12f
#define NCH 32   // i-chunks per sector in k3

// ws layout (float offsets)
enum {
  OFF_U    = 0,            // U_ni            [24][1024]
  OFF_RMAX = 24576,        // loc-logit max   [24][1024]
  OFF_SEXP = 49152,        // loc sumexp      [24][1024]
  OFF_D    = 73728,        // D_ni            [24][1024]
  OFF_XP   = 98304         // X_pred          [24][1024]
};

// ---- mask handling: bool masks may arrive as packed bytes or 32-bit words.
// 32-bit words are 0 / 1 (int) or 0 / 0x3F800000 (float) -> word!=0 works for
// both. Packed bytes produce words like 0x01010100 -> detect and read bytes.
__device__ __forceinline__ bool masks_are_bytes(const void* hm, const void* gm) {
  const unsigned int* hw = (const unsigned int*)hm;
  const unsigned int* gw = (const unsigned int*)gm;
  bool b = false;
  #pragma unroll
  for (int k = 0; k < 6; k++) {   // first 24 bytes of each — safe in all layouts
    unsigned int a = hw[k], c = gw[k];
    if (a != 0u && a != 1u && a != 0x3F800000u) b = true;
    if (c != 0u && c != 1u && c != 0x3F800000u) b = true;
  }
  return b;
}
__device__ __forceinline__ bool loc_flag(const void* hm, const void* gm, int n) {
  bool bytes = masks_are_bytes(hm, gm);
  bool hv = bytes ? (((const unsigned char*)hm)[n] != 0)
                  : (((const unsigned int*)hm)[n] != 0u);
  bool gv = bytes ? (((const unsigned char*)gm)[n] != 0)
                  : (((const unsigned int*)gm)[n] != 0u);
  return gv && !hv;
}

// K1: per-(n,i) row — location-softmax stats + composite disutility U_ni.
// 256 threads = 4 waves = 4 rows, all same sector n; per-n rows staged in LDS.
__global__ __launch_bounds__(256) void k1_rows(
    const float* __restrict__ t, const float* __restrict__ price,
    const float* __restrict__ h, const float* __restrict__ A_ni,
    const float* __restrict__ beta, const float* __restrict__ lamda,
    const void* __restrict__ housing, const void* __restrict__ genflux,
    float* __restrict__ ws) {
  const int n  = blockIdx.x >> 8;            // 256 blocks per sector
  const int i0 = (blockIdx.x & 255) * 4;
  __shared__ float pc_s[ZDIM];               // lamda*(price+h)
  __shared__ float cc_s[ZDIM];               // slog(A) - beta*pc
  const float bn = beta[n], ln = lamda[n];
  for (int j = threadIdx.x; j < ZDIM; j += 256) {
    float pc = ln * (price[n * ZDIM + j] + h[n * ZDIM + j]);
    float sa = logf(fmaxf(A_ni[n * ZDIM + j], EPS_F));
    pc_s[j] = pc;
    cc_s[j] = sa - bn * pc;
  }
  __syncthreads();
  const int wave = threadIdx.x >> 6, lane = threadIdx.x & 63;
  const int i = i0 + wave;
  const int row = n * ZDIM + i;
  if (!loc_flag(housing, genflux, n)) {
    // Pr = eye  =>  U_ni = U_nij[i,i]
    if (lane == 0)
      ws[OFF_U + row] = pc_s[i] + t[(size_t)row * ZDIM + i];
    return;
  }
  const float4* t4  = (const float4*)(t + (size_t)row * ZDIM);
  const float4* pc4 = (const float4*)pc_s;
  const float4* cc4 = (const float4*)cc_s;
  float lg[16], uv[16];
  float mx = -INFINITY;
  #pragma unroll
  for (int k = 0; k < 4; k++) {
    const int f = lane + 64 * k;
    float4 tv = t4[f];
    float4 pv = pc4[f];
    float4 cv = cc4[f];
    uv[4*k+0] = pv.x + tv.x;  lg[4*k+0] = cv.x - bn * tv.x;
    uv[4*k+1] = pv.y + tv.y;  lg[4*k+1] = cv.y - bn * tv.y;
    uv[4*k+2] = pv.z + tv.z;  lg[4*k+2] = cv.z - bn * tv.z;
    uv[4*k+3] = pv.w + tv.w;  lg[4*k+3] = cv.w - bn * tv.w;
    mx = fmaxf(mx, fmaxf(fmaxf(lg[4*k], lg[4*k+1]), fmaxf(lg[4*k+2], lg[4*k+3])));
  }
  #pragma unroll
  for (int off = 32; off >= 1; off >>= 1)
    mx = fmaxf(mx, __shfl_xor(mx, off));
  float se = 0.f, su = 0.f;
  #pragma unroll
  for (int k = 0; k < 16; k++) {
    float e = __expf(lg[k] - mx);
    se += e;
    su = fmaf(e, uv[k], su);
  }
  #pragma unroll
  for (int off = 32; off >= 1; off >>= 1) {
    se += __shfl_xor(se, off);
    su += __shfl_xor(su, off);
  }
  if (lane == 0) {
    ws[OFF_U + row]    = su / se;
    ws[OFF_RMAX + row] = mx;
    ws[OFF_SEXP + row] = se;
  }
}

// K2: substitution softmax over n + total demand D_ni.
// Lane layout: 32-lane half-wave per zone i; lane n<24 owns sector n.
// Softmax over n = 5-step __shfl_xor butterfly within the half-wave.
// Per-thread state is ~12 scalars -> no scratch spill (old version spilled
// five float[24] arrays and ran 114 us).
__global__ __launch_bounds__(256) void k2_demand(
    const float* __restrict__ demin, const float* __restrict__ demax,
    const float* __restrict__ delta, const float* __restrict__ omega,
    const float* __restrict__ sigma, const float* __restrict__ Kn,
    const float* __restrict__ attractor, const float* __restrict__ exogd,
    const float* __restrict__ X0, const float* __restrict__ exogp,
    const void* __restrict__ housing, const void* __restrict__ genflux,
    float* __restrict__ ws) {
  const int wave = threadIdx.x >> 6;          // 0..3
  const int lane = threadIdx.x & 63;
  const int half = lane >> 5;                 // 0..1 (two zones per wave)
  const int n    = lane & 31;                 // sector in lane; n<24 active
  const int i    = blockIdx.x * 8 + wave * 2 + half;   // 128 blocks -> 0..1023
  const bool nv  = (n < MDIM);
  float Uv = 0.f, asl = NEG_INF_F;
  if (nv) {
    Uv  = ws[OFF_U + n * ZDIM + i];
    asl = logf(fmaxf(attractor[n * ZDIM + i], EPS_F));
  }
  float acc = 0.f;
  for (int m = 0; m < MDIM; m++) {
    const float Xt  = X0[m * ZDIM + i] + exogp[m * ZDIM + i];
    const float sig = sigma[m];
    float dm = 0.f, dd = 0.f, dl = 0.f, om = 0.f, kn = 0.f;
    if (nv) {
      dm = demin[m * MDIM + n];
      dd = demax[m * MDIM + n] - dm;
      dl = delta[m * MDIM + n];
      om = omega[m * MDIM + n];
      kn = Kn[m * MDIM + n];
    }
    const float a = dm + dd * __expf(-dl * Uv);
    const bool valid = nv && (kn > 0.f);
    const float l = valid ? asl - sig * om * a * Uv : NEG_INF_F;
    float mx = l;
    #pragma unroll
    for (int off = 16; off >= 1; off >>= 1)
      mx = fmaxf(mx, __shfl_xor(mx, off));    // stays within 32-lane half
    float e = valid ? __expf(l - mx) : 0.f;
    float se = e;
    #pragma unroll
    for (int off = 16; off >= 1; off >>= 1)
      se += __shfl_xor(se, off);
    const float S = (valid && se > 0.f) ? e / se : 1.0f;
    if (nv) acc = fmaf(a * S, Xt, acc);
  }
  if (nv) {
    const float Dv = exogd[n * ZDIM + i] + acc;
    ws[OFF_D + n * ZDIM + i]  = Dv;
    // eye-sector X_pred = D; loc sectors accumulated by k3 from 0
    ws[OFF_XP + n * ZDIM + i] = loc_flag(housing, genflux, n) ? 0.f : Dv;
  }
}

// K3: X_pred[n,j] += sum_i (D_i/sumexp_i) * exp(c_j - max_i - beta*t[n,i,j])
// grid = (n, i-chunk); loc sectors only; second (L3-warm) pass over t.
__global__ __launch_bounds__(256) void k3_xpred(
    const float* __restrict__ t, const float* __restrict__ price,
    const float* __restrict__ h, const float* __restrict__ A_ni,
    const float* __restrict__ beta, const float* __restrict__ lamda,
    const void* __restrict__ housing, const void* __restrict__ genflux,
    float* __restrict__ ws) {
  const int n = blockIdx.x / NCH, ic = blockIdx.x % NCH;
  if (!loc_flag(housing, genflux, n)) return;
  const int tj = threadIdx.x;                       // float4 index over j
  const float bn = beta[n], ln = lamda[n];
  const float4 pr = ((const float4*)(price + n * ZDIM))[tj];
  const float4 hh = ((const float4*)(h     + n * ZDIM))[tj];
  const float4 aa = ((const float4*)(A_ni  + n * ZDIM))[tj];
  const float c0 = logf(fmaxf(aa.x, EPS_F)) - bn * (ln * (pr.x + hh.x));
  const float c1 = logf(fmaxf(aa.y, EPS_F)) - bn * (ln * (pr.y + hh.y));
  const float c2 = logf(fmaxf(aa.z, EPS_F)) - bn * (ln * (pr.z + hh.z));
  const float c3 = logf(fmaxf(aa.w, EPS_F)) - bn * (ln * (pr.w + hh.w));
  const float4* t4 = (const float4*)t;
  float x0 = 0.f, x1 = 0.f, x2 = 0.f, x3 = 0.f;
  for (int ii = 0; ii < ZDIM / NCH; ii++) {
    const int i = ic * (ZDIM / NCH) + ii;
    const int row = n * ZDIM + i;
    const float mx = ws[OFF_RMAX + row];
    const float w  = ws[OFF_D + row] / ws[OFF_SEXP + row];
    float4 tv = t4[(size_t)row * (ZDIM / 4) + tj];
    x0 = fmaf(w, __expf(c0 - mx - bn * tv.x), x0);
    x1 = fmaf(w, __expf(c1 - mx - bn * tv.y), x1);
    x2 = fmaf(w, __expf(c2 - mx - bn * tv.z), x2);
    x3 = fmaf(w, __expf(c3 - mx - bn * tv.w), x3);
  }
  float* xp = ws + OFF_XP + n * ZDIM + tj * 4;
  atomicAdd(xp + 0, x0);
  atomicAdd(xp + 1, x1);
  atomicAdd(xp + 2, x2);
  atomicAdd(xp + 3, x3);
}

// K4: loss = mean((X_pred - X_target)^2). Single block -> direct write, no memset.
__global__ __launch_bounds__(1024) void k4_loss(
    const float* __restrict__ Xtg, const float* __restrict__ ws,
    float* __restrict__ out) {
  float s = 0.f;
  for (int e = threadIdx.x; e < MDIM * ZDIM; e += 1024) {
    float d = ws[OFF_XP + e] - Xtg[e];
    s = fmaf(d, d, s);
  }
  #pragma unroll
  for (int off = 32; off >= 1; off >>= 1) s += __shfl_xor(s, off);
  __shared__ float red[16];
  const int w = threadIdx.x >> 6, lane = threadIdx.x & 63;
  if (lane == 0) red[w] = s;
  __syncthreads();
  if (threadIdx.x == 0) {
    float tot = 0.f;
    #pragma unroll
    for (int k = 0; k < 16; k++) tot += red[k];
    *out = tot * (1.0f / (MDIM * ZDIM));
  }
}

extern "C" void kernel_launch(void* const* d_in, const int* in_sizes, int n_in,
                              void* d_out, int out_size, void* d_ws, size_t ws_size,
                              hipStream_t stream) {
  (void)in_sizes; (void)n_in; (void)out_size; (void)ws_size;
  const float* h       = (const float*)d_in[0];
  const float* price   = (const float*)d_in[1];
  const float* t       = (const float*)d_in[2];
  const float* demin   = (const float*)d_in[3];
  const float* demax   = (const float*)d_in[4];
  const float* delta   = (const float*)d_in[5];
  const float* omega   = (const float*)d_in[6];
  const float* sigma   = (const float*)d_in[7];
  const float* Kn      = (const float*)d_in[8];
  const float* attract = (const float*)d_in[9];
  const float* beta    = (const float*)d_in[10];
  const float* lamda   = (const float*)d_in[11];
  const float* A_ni    = (const float*)d_in[12];
  const float* exogd   = (const float*)d_in[13];
  const float* exogp   = (const float*)d_in[14];
  const float* X0      = (const float*)d_in[15];
  const float* Xtg     = (const float*)d_in[16];
  const void*  housing = d_in[17];
  const void*  genflux = d_in[18];
  float* ws  = (float*)d_ws;
  float* out = (float*)d_out;

  k1_rows<<<MDIM * 256, 256, 0, stream>>>(t, price, h, A_ni, beta, lamda,
                                          housing, genflux, ws);
  k2_demand<<<128, 256, 0, stream>>>(demin, demax, delta, omega, sigma, Kn,
                                     attract, exogd, X0, exogp, housing, genflux, ws);
  k3_xpred<<<MDIM * NCH, 256, 0, stream>>>(t, price, h, A_ni, beta, lamda,
                                           housing, genflux, ws);
  k4_loss<<<1, 1024, 0, stream>>>(Xtg, ws, out);
}